// Round 1
// baseline (397.067 us; speedup 1.0000x reference)
//
#include <hip/hip_runtime.h>
#include <stdint.h>

typedef unsigned short u16;
typedef short short8 __attribute__((ext_vector_type(8)));
typedef float f32x4 __attribute__((ext_vector_type(4)));

#define DM    2048
#define NH    16
#define NKV   4
#define DH    128
#define TQKV  3072
#define NB    2
#define SEQL  2048
#define MROWS (NB * SEQL)      // 4096
#define QDIM  (NH * DH)        // 2048
#define KVDIM (NKV * DH)       // 512
#define QSCALE 0.08838834764831845f

#define MFMA16(a, b, c) __builtin_amdgcn_mfma_f32_16x16x32_bf16((a), (b), (c), 0, 0, 0)

__device__ __forceinline__ u16 f2bf(float f) {
  uint32_t u = __float_as_uint(f);
  u += 0x7fffu + ((u >> 16) & 1u);
  return (u16)(u >> 16);
}
__device__ __forceinline__ float bf2f(u16 h) {
  return __uint_as_float(((uint32_t)h) << 16);
}
__device__ __forceinline__ void gload16(const u16* g, u16* l) {
  __builtin_amdgcn_global_load_lds((__attribute__((address_space(1))) void*)(u16*)g,
                                   (__attribute__((address_space(3))) void*)l, 16, 0, 0);
}

// ---------------- f32 -> bf16 convert (vectorized) ----------------
__global__ void k_f32_to_bf16(const float* __restrict__ src, u16* __restrict__ dst, int n) {
  int i = (blockIdx.x * blockDim.x + threadIdx.x) * 4;
  if (i >= n) return;
  float4 v = *reinterpret_cast<const float4*>(src + i);
  u16 o0 = f2bf(v.x), o1 = f2bf(v.y), o2 = f2bf(v.z), o3 = f2bf(v.w);
  u16* d = dst + i;
  d[0] = o0; d[1] = o1; d[2] = o2; d[3] = o3;
}

// ---------------- tiled transpose f32 [K][N] -> bf16 [rowOff+N][K] ----------------
__global__ void k_transpose_f32_bf16(const float* __restrict__ src, u16* __restrict__ dst,
                                     int K, int N, int rowOff, int dstLd) {
  __shared__ float t[32][33];
  const int n0 = blockIdx.x * 32, k0 = blockIdx.y * 32;
  const int tx = threadIdx.x, ty = threadIdx.y;
#pragma unroll
  for (int i = ty; i < 32; i += 8)
    t[i][tx] = src[(size_t)(k0 + i) * N + (n0 + tx)];
  __syncthreads();
#pragma unroll
  for (int i = ty; i < 32; i += 8)
    dst[(size_t)(rowOff + n0 + i) * dstLd + (k0 + tx)] = f2bf(t[tx][i]);
}

// ---------------- tiled transpose bf16 [R][C] -> bf16 [C][R], batched over z ----------------
__global__ void k_transpose_bf16(const u16* __restrict__ src, u16* __restrict__ dst, int R, int C) {
  __shared__ u16 t[32][33];
  const size_t zoff = (size_t)blockIdx.z * R * C;
  const int c0 = blockIdx.x * 32, r0 = blockIdx.y * 32;
  const int tx = threadIdx.x, ty = threadIdx.y;
#pragma unroll
  for (int i = ty; i < 32; i += 8)
    t[i][tx] = src[zoff + (size_t)(r0 + i) * C + (c0 + tx)];
  __syncthreads();
#pragma unroll
  for (int i = ty; i < 32; i += 8)
    dst[zoff + (size_t)(c0 + i) * R + (r0 + tx)] = t[tx][i];
}

// ---------------- bf16 GEMM: C[M][N] = A[M][K] * Bt[N][K]^T ----------------
// 128x128 tile, BK=32, 256 threads (4 waves, each 64x64), global_load_lds staging,
// double-buffered LDS, 2-phase schedule.
template <int OUTBF>
__global__ __launch_bounds__(256) void k_gemm_bt(const u16* __restrict__ A, const u16* __restrict__ Bt,
                                                 float* __restrict__ Cf, u16* __restrict__ Cb,
                                                 int M, int N, int K) {
  __shared__ u16 As[2][128 * 32];
  __shared__ u16 Bs[2][128 * 32];
  const int tid = threadIdx.x;
  const int m0 = blockIdx.x * 128;
  const int n0 = blockIdx.y * 128;
  const int r  = tid >> 2;
  const int c8 = (tid & 3) << 3;
  const u16* Ag0 = A  + (size_t)(m0 + r) * K + c8;
  const u16* Ag1 = A  + (size_t)(m0 + 64 + r) * K + c8;
  const u16* Bg0 = Bt + (size_t)(n0 + r) * K + c8;
  const u16* Bg1 = Bt + (size_t)(n0 + 64 + r) * K + c8;

  auto stage = [&](int buf, int kt) {
    const int kg = kt * 32;
    gload16(Ag0 + kg, &As[buf][tid * 8]);
    gload16(Ag1 + kg, &As[buf][2048 + tid * 8]);
    gload16(Bg0 + kg, &Bs[buf][tid * 8]);
    gload16(Bg1 + kg, &Bs[buf][2048 + tid * 8]);
  };

  f32x4 acc[4][4];
#pragma unroll
  for (int i = 0; i < 4; ++i)
#pragma unroll
    for (int j = 0; j < 4; ++j) acc[i][j] = (f32x4){0.f, 0.f, 0.f, 0.f};

  const int wv = tid >> 6, ln = tid & 63;
  const int wr = (wv >> 1) * 64, wc = (wv & 1) * 64;
  const int lr = ln & 15, lko = (ln >> 4) * 8;

  stage(0, 0);
  __syncthreads();

  const int nk = K >> 5;
  for (int kt = 0; kt < nk; ++kt) {
    const int cur = kt & 1;
    if (kt + 1 < nk) stage(cur ^ 1, kt + 1);
    short8 af[4], bf[4];
#pragma unroll
    for (int i = 0; i < 4; ++i)
      af[i] = *reinterpret_cast<const short8*>(&As[cur][(wr + i * 16 + lr) * 32 + lko]);
#pragma unroll
    for (int i = 0; i < 4; ++i)
      bf[i] = *reinterpret_cast<const short8*>(&Bs[cur][(wc + i * 16 + lr) * 32 + lko]);
#pragma unroll
    for (int i = 0; i < 4; ++i)
#pragma unroll
      for (int j = 0; j < 4; ++j)
        acc[i][j] = MFMA16(af[i], bf[j], acc[i][j]);
    __syncthreads();
  }

  const int rg = (ln >> 4) * 4;
#pragma unroll
  for (int i = 0; i < 4; ++i) {
#pragma unroll
    for (int j = 0; j < 4; ++j) {
      const int row = m0 + wr + i * 16 + rg;
      const int col = n0 + wc + j * 16 + lr;
#pragma unroll
      for (int q = 0; q < 4; ++q) {
        float v = acc[i][j][q];
        if (OUTBF) Cb[(size_t)(row + q) * N + col] = f2bf(v);
        else       Cf[(size_t)(row + q) * N + col] = v;
      }
    }
  }
}

// ---------------- depthwise causal conv1d + residual + route to Q/K/V ----------------
__global__ void k_conv_route(const u16* __restrict__ qkv, const float* __restrict__ cw,
                             u16* __restrict__ Qh, u16* __restrict__ Kh, u16* __restrict__ Vsd) {
  const int row = blockIdx.x;            // b*SEQL + s
  const int b = row >> 11, s = row & 2047;
  const int c = threadIdx.x * 8;         // 384 threads -> 3072 channels
  float x[4][8];
#pragma unroll
  for (int k = 0; k < 4; ++k) {
    const int sr = s + k - 3;
    if (sr < 0) {
#pragma unroll
      for (int j = 0; j < 8; ++j) x[k][j] = 0.f;
    } else {
      short8 v = *reinterpret_cast<const short8*>(&qkv[(size_t)(b * SEQL + sr) * TQKV + c]);
#pragma unroll
      for (int j = 0; j < 8; ++j) x[k][j] = bf2f((u16)v[j]);
    }
  }
  float o[8];
#pragma unroll
  for (int j = 0; j < 8; ++j) {
    float4 w4 = *reinterpret_cast<const float4*>(&cw[(c + j) * 4]);
    o[j] = x[3][j] + x[0][j] * w4.x + x[1][j] * w4.y + x[2][j] * w4.z + x[3][j] * w4.w;
  }
  short8 ov;
  if (c < QDIM) {
#pragma unroll
    for (int j = 0; j < 8; ++j) ov[j] = (short)f2bf(o[j] * QSCALE);
    const int h = c >> 7, d = c & 127;
    *reinterpret_cast<short8*>(&Qh[((size_t)(b * NH + h) * SEQL + s) * DH + d]) = ov;
  } else if (c < QDIM + KVDIM) {
#pragma unroll
    for (int j = 0; j < 8; ++j) ov[j] = (short)f2bf(o[j]);
    const int cc = c - QDIM;
    const int h = cc >> 7, d = cc & 127;
    *reinterpret_cast<short8*>(&Kh[((size_t)(b * NKV + h) * SEQL + s) * DH + d]) = ov;
  } else {
#pragma unroll
    for (int j = 0; j < 8; ++j) ov[j] = (short)f2bf(o[j]);
    const int cc = c - QDIM - KVDIM;
    const int h = cc >> 7, d = cc & 127;
    *reinterpret_cast<short8*>(&Vsd[((size_t)(b * NKV + h) * SEQL + s) * DH + d]) = ov;
  }
}

// ---------------- GQA causal flash attention ----------------
// Grid: (S/64, NH, NB). Block: 256 = 4 waves; wave w handles q rows qb*64+w*16 .. +15.
// KV tiles of 32. K tile LDS [32][128] (XOR-swizzled, (row&7)*8), V tile LDS [128][32]
// d-major ((d&3)*8 swizzle), per-wave P buffer [16][32] ((row&3)*8 swizzle).
__global__ __launch_bounds__(256) void k_attn(const u16* __restrict__ Qh, const u16* __restrict__ Kh,
                                              const u16* __restrict__ Vt, u16* __restrict__ att) {
  __shared__ u16 Ks[32 * 128];
  __shared__ u16 Vs[128 * 32];
  __shared__ u16 Ps[4][16 * 32];
  const int qb = blockIdx.x, h = blockIdx.y, b = blockIdx.z;
  const int kvh = h >> 2;
  const int tid = threadIdx.x, wv = tid >> 6, ln = tid & 63;
  const int lr = ln & 15, lg = ln >> 4;
  const int sq = qb * 64 + wv * 16;

  const u16* qbase = Qh + ((size_t)(b * NH + h) * SEQL + (sq + lr)) * DH;
  short8 aq[4];
#pragma unroll
  for (int kc = 0; kc < 4; ++kc)
    aq[kc] = *reinterpret_cast<const short8*>(qbase + kc * 32 + lg * 8);

  f32x4 oacc[8];
#pragma unroll
  for (int cb = 0; cb < 8; ++cb) oacc[cb] = (f32x4){0.f, 0.f, 0.f, 0.f};
  float mrow[4], lrow[4];
#pragma unroll
  for (int rr = 0; rr < 4; ++rr) { mrow[rr] = -1e30f; lrow[rr] = 0.f; }

  const u16* kg = Kh + (size_t)(b * NKV + kvh) * SEQL * DH;
  const u16* vg = Vt + (size_t)(b * NKV + kvh) * DH * SEQL;
  const int ntiles = qb * 2 + 2;
  const int krow = tid >> 3, kcol = (tid & 7) << 4;   // K staging: 2x short8 per thread
  const int vrow = tid >> 1, vcol = (tid & 1) << 4;   // V staging: 2x short8 per thread

  for (int t = 0; t < ntiles; ++t) {
    const int kvs = t * 32;
    __syncthreads();
    {
      const u16* s0 = kg + (size_t)(kvs + krow) * DH + kcol;
      short8 v0 = *reinterpret_cast<const short8*>(s0);
      short8 v1 = *reinterpret_cast<const short8*>(s0 + 8);
      const int sw = (krow & 7) * 8;
      *reinterpret_cast<short8*>(&Ks[krow * 128 + (kcol ^ sw)]) = v0;
      *reinterpret_cast<short8*>(&Ks[krow * 128 + ((kcol + 8) ^ sw)]) = v1;

      const u16* t0 = vg + (size_t)vrow * SEQL + kvs + vcol;
      short8 w0 = *reinterpret_cast<const short8*>(t0);
      short8 w1 = *reinterpret_cast<const short8*>(t0 + 8);
      const int sv = (vrow & 3) * 8;
      *reinterpret_cast<short8*>(&Vs[vrow * 32 + (vcol ^ sv)]) = w0;
      *reinterpret_cast<short8*>(&Vs[vrow * 32 + ((vcol + 8) ^ sv)]) = w1;
    }
    __syncthreads();

    // S = Q K^T (scale pre-folded into Q)
    f32x4 sc[2];
    sc[0] = (f32x4){0.f, 0.f, 0.f, 0.f};
    sc[1] = (f32x4){0.f, 0.f, 0.f, 0.f};
#pragma unroll
    for (int cb = 0; cb < 2; ++cb) {
      const int krw = cb * 16 + lr;
      const int swr = (krw & 7) * 8;
#pragma unroll
      for (int kc = 0; kc < 4; ++kc) {
        short8 bk = *reinterpret_cast<const short8*>(&Ks[krw * 128 + ((kc * 32 + lg * 8) ^ swr)]);
        sc[cb] = MFMA16(aq[kc], bk, sc[cb]);
      }
    }
    if (kvs + 31 > sq) {
#pragma unroll
      for (int cb = 0; cb < 2; ++cb)
#pragma unroll
        for (int rr = 0; rr < 4; ++rr) {
          const int qg = sq + lg * 4 + rr;
          const int kvg = kvs + cb * 16 + lr;
          if (kvg > qg) sc[cb][rr] = -1e30f;
        }
    }
    // online softmax
    float pr0[4], pr1[4];
#pragma unroll
    for (int rr = 0; rr < 4; ++rr) {
      float tm = fmaxf(sc[0][rr], sc[1][rr]);
#pragma unroll
      for (int off = 1; off < 16; off <<= 1) tm = fmaxf(tm, __shfl_xor(tm, off));
      const float nm = fmaxf(mrow[rr], tm);
      const float scl = __expf(mrow[rr] - nm);
      const float p0 = __expf(sc[0][rr] - nm);
      const float p1 = __expf(sc[1][rr] - nm);
      float ps = p0 + p1;
#pragma unroll
      for (int off = 1; off < 16; off <<= 1) ps += __shfl_xor(ps, off);
      lrow[rr] = lrow[rr] * scl + ps;
      mrow[rr] = nm;
      pr0[rr] = p0; pr1[rr] = p1;
#pragma unroll
      for (int cb = 0; cb < 8; ++cb) oacc[cb][rr] *= scl;
    }
    // P -> LDS (bf16, swizzled)
#pragma unroll
    for (int rr = 0; rr < 4; ++rr) {
      const int prow = lg * 4 + rr;
      const int swp = (prow & 3) * 8;
      Ps[wv][prow * 32 + ((lr) ^ swp)]        = f2bf(pr0[rr]);
      Ps[wv][prow * 32 + ((16 + lr) ^ swp)]   = f2bf(pr1[rr]);
    }
    asm volatile("s_waitcnt lgkmcnt(0)" ::: "memory");
    short8 pa = *reinterpret_cast<const short8*>(&Ps[wv][lr * 32 + ((lg * 8) ^ ((lr & 3) * 8))]);
    // O += P V
#pragma unroll
    for (int cb = 0; cb < 8; ++cb) {
      const int dr = cb * 16 + lr;
      short8 bv = *reinterpret_cast<const short8*>(&Vs[dr * 32 + ((lg * 8) ^ ((dr & 3) * 8))]);
      oacc[cb] = MFMA16(pa, bv, oacc[cb]);
    }
  }
  // epilogue
#pragma unroll
  for (int rr = 0; rr < 4; ++rr) {
    const float inv = 1.0f / lrow[rr];
    const int srow = sq + lg * 4 + rr;
    u16* orow = att + (size_t)(b * SEQL + srow) * QDIM + h * DH;
#pragma unroll
    for (int cb = 0; cb < 8; ++cb)
      orow[cb * 16 + lr] = f2bf(oacc[cb][rr] * inv);
  }
}

// ---------------- launch ----------------
extern "C" void kernel_launch(void* const* d_in, const int* in_sizes, int n_in,
                              void* d_out, int out_size, void* d_ws, size_t ws_size,
                              hipStream_t stream) {
  const float* hin = (const float*)d_in[0];
  const float* wq  = (const float*)d_in[1];
  const float* wk  = (const float*)d_in[2];
  const float* wvv = (const float*)d_in[3];
  const float* wo  = (const float*)d_in[4];
  const float* cw  = (const float*)d_in[5];
  float* out = (float*)d_out;
  char* ws = (char*)d_ws;

  u16* h_bf = (u16*)(ws + 0);                       // 16,777,216  [4096][2048]
  u16* Wt   = (u16*)(ws + 16777216);                // 12,582,912  [3072][2048]
  u16* Wot  = (u16*)(ws + 29360128);                //  8,388,608  [2048][2048]
  u16* Qh   = (u16*)(ws + 37748736);                // 16,777,216  [B][NH][S][DH]
  u16* Kh   = (u16*)(ws + 54525952);                //  4,194,304  [B][NKV][S][DH]
  u16* Vsd  = (u16*)(ws + 58720256);                //  4,194,304  [B][NKV][S][DH]
  u16* Vt   = (u16*)(ws + 62914560);                //  4,194,304  [B][NKV][DH][S]
  u16* att  = (u16*)(ws + 67108864);                // 16,777,216  [4096][2048]
  u16* qkv  = (u16*)d_out;                          // scratch reuse: 25,165,824 < 33,554,432

  dim3 tb(32, 8);
  k_f32_to_bf16<<<8192, 256, 0, stream>>>(hin, h_bf, MROWS * DM);
  k_transpose_f32_bf16<<<dim3(64, 64), tb, 0, stream>>>(wq, Wt, 2048, 2048, 0, 2048);
  k_transpose_f32_bf16<<<dim3(16, 64), tb, 0, stream>>>(wk, Wt, 2048, 512, 2048, 2048);
  k_transpose_f32_bf16<<<dim3(16, 64), tb, 0, stream>>>(wvv, Wt, 2048, 512, 2560, 2048);
  k_transpose_f32_bf16<<<dim3(64, 64), tb, 0, stream>>>(wo, Wot, 2048, 2048, 0, 2048);
  k_gemm_bt<1><<<dim3(32, 24), 256, 0, stream>>>(h_bf, Wt, nullptr, qkv, MROWS, TQKV, DM);
  k_conv_route<<<MROWS, 384, 0, stream>>>(qkv, cw, Qh, Kh, Vsd);
  k_transpose_bf16<<<dim3(4, 64, NB * NKV), tb, 0, stream>>>(Vsd, Vt, SEQL, DH);
  k_attn<<<dim3(SEQL / 64, NH, NB), 256, 0, stream>>>(Qh, Kh, Vt, att);
  k_gemm_bt<0><<<dim3(32, 16), 256, 0, stream>>>(att, Wot, out, nullptr, MROWS, DM, DM);
}

// Round 2
// 251.801 us; speedup vs baseline: 1.5769x; 1.5769x over previous
//
#include <hip/hip_runtime.h>
#include <stdint.h>

typedef unsigned short u16;
typedef short short8 __attribute__((ext_vector_type(8)));
typedef float f32x4 __attribute__((ext_vector_type(4)));
typedef float f32x16 __attribute__((ext_vector_type(16)));

#define DM    2048
#define NH    16
#define NKV   4
#define DH    128
#define TQKV  3072
#define NB    2
#define SEQL  2048
#define MROWS (NB * SEQL)      // 4096
#define QDIM  (NH * DH)        // 2048
#define KVDIM (NKV * DH)       // 512
#define QSCALE 0.08838834764831845f

#define MFMA16(a, b, c) __builtin_amdgcn_mfma_f32_16x16x32_bf16((a), (b), (c), 0, 0, 0)
#define MFMA32(a, b, c) __builtin_amdgcn_mfma_f32_32x32x16_bf16((a), (b), (c), 0, 0, 0)

__device__ __forceinline__ u16 f2bf(float f) {
  uint32_t u = __float_as_uint(f);
  u += 0x7fffu + ((u >> 16) & 1u);
  return (u16)(u >> 16);
}
__device__ __forceinline__ float bf2f(u16 h) {
  return __uint_as_float(((uint32_t)h) << 16);
}
__device__ __forceinline__ void gload16(const u16* g, u16* l) {
  __builtin_amdgcn_global_load_lds((__attribute__((address_space(1))) void*)(u16*)g,
                                   (__attribute__((address_space(3))) void*)l, 16, 0, 0);
}
__device__ __forceinline__ uint32_t cvtpk(float lo, float hi) {
  uint32_t r;
  asm("v_cvt_pk_bf16_f32 %0, %1, %2" : "=v"(r) : "v"(lo), "v"(hi));
  return r;
}
__device__ __forceinline__ void swapln(uint32_t& a, uint32_t& b) {
  asm volatile("v_permlane32_swap_b32 %0, %1" : "+v"(a), "+v"(b));
}

// ---------------- f32 -> bf16 convert (vectorized) ----------------
__global__ void k_f32_to_bf16(const float* __restrict__ src, u16* __restrict__ dst, int n) {
  int i = (blockIdx.x * blockDim.x + threadIdx.x) * 4;
  if (i >= n) return;
  float4 v = *reinterpret_cast<const float4*>(src + i);
  u16 o0 = f2bf(v.x), o1 = f2bf(v.y), o2 = f2bf(v.z), o3 = f2bf(v.w);
  u16* d = dst + i;
  d[0] = o0; d[1] = o1; d[2] = o2; d[3] = o3;
}

// ---------------- tiled transpose f32 [K][N] -> bf16 [rowOff+N][K] ----------------
__global__ void k_transpose_f32_bf16(const float* __restrict__ src, u16* __restrict__ dst,
                                     int K, int N, int rowOff, int dstLd) {
  __shared__ float t[32][33];
  const int n0 = blockIdx.x * 32, k0 = blockIdx.y * 32;
  const int tx = threadIdx.x, ty = threadIdx.y;
#pragma unroll
  for (int i = ty; i < 32; i += 8)
    t[i][tx] = src[(size_t)(k0 + i) * N + (n0 + tx)];
  __syncthreads();
#pragma unroll
  for (int i = ty; i < 32; i += 8)
    dst[(size_t)(rowOff + n0 + i) * dstLd + (k0 + tx)] = f2bf(t[tx][i]);
}

// ---------------- tiled transpose bf16 [R][C] -> bf16 [C][R], batched over z ----------------
__global__ void k_transpose_bf16(const u16* __restrict__ src, u16* __restrict__ dst, int R, int C) {
  __shared__ u16 t[32][33];
  const size_t zoff = (size_t)blockIdx.z * R * C;
  const int c0 = blockIdx.x * 32, r0 = blockIdx.y * 32;
  const int tx = threadIdx.x, ty = threadIdx.y;
#pragma unroll
  for (int i = ty; i < 32; i += 8)
    t[i][tx] = src[zoff + (size_t)(r0 + i) * C + (c0 + tx)];
  __syncthreads();
#pragma unroll
  for (int i = ty; i < 32; i += 8)
    dst[zoff + (size_t)(c0 + i) * R + (r0 + tx)] = t[tx][i];
}

// ---------------- bf16 GEMM: C[M][N] = A[M][K] * Bt[N][K]^T ----------------
template <int OUTBF>
__global__ __launch_bounds__(256) void k_gemm_bt(const u16* __restrict__ A, const u16* __restrict__ Bt,
                                                 float* __restrict__ Cf, u16* __restrict__ Cb,
                                                 int M, int N, int K) {
  __shared__ u16 As[2][128 * 32];
  __shared__ u16 Bs[2][128 * 32];
  const int tid = threadIdx.x;
  const int m0 = blockIdx.x * 128;
  const int n0 = blockIdx.y * 128;
  const int r  = tid >> 2;
  const int c8 = (tid & 3) << 3;
  const u16* Ag0 = A  + (size_t)(m0 + r) * K + c8;
  const u16* Ag1 = A  + (size_t)(m0 + 64 + r) * K + c8;
  const u16* Bg0 = Bt + (size_t)(n0 + r) * K + c8;
  const u16* Bg1 = Bt + (size_t)(n0 + 64 + r) * K + c8;

  auto stage = [&](int buf, int kt) {
    const int kg = kt * 32;
    gload16(Ag0 + kg, &As[buf][tid * 8]);
    gload16(Ag1 + kg, &As[buf][2048 + tid * 8]);
    gload16(Bg0 + kg, &Bs[buf][tid * 8]);
    gload16(Bg1 + kg, &Bs[buf][2048 + tid * 8]);
  };

  f32x4 acc[4][4];
#pragma unroll
  for (int i = 0; i < 4; ++i)
#pragma unroll
    for (int j = 0; j < 4; ++j) acc[i][j] = (f32x4){0.f, 0.f, 0.f, 0.f};

  const int wv = tid >> 6, ln = tid & 63;
  const int wr = (wv >> 1) * 64, wc = (wv & 1) * 64;
  const int lr = ln & 15, lko = (ln >> 4) * 8;

  stage(0, 0);
  __syncthreads();

  const int nk = K >> 5;
  for (int kt = 0; kt < nk; ++kt) {
    const int cur = kt & 1;
    if (kt + 1 < nk) stage(cur ^ 1, kt + 1);
    short8 af[4], bf[4];
#pragma unroll
    for (int i = 0; i < 4; ++i)
      af[i] = *reinterpret_cast<const short8*>(&As[cur][(wr + i * 16 + lr) * 32 + lko]);
#pragma unroll
    for (int i = 0; i < 4; ++i)
      bf[i] = *reinterpret_cast<const short8*>(&Bs[cur][(wc + i * 16 + lr) * 32 + lko]);
#pragma unroll
    for (int i = 0; i < 4; ++i)
#pragma unroll
      for (int j = 0; j < 4; ++j)
        acc[i][j] = MFMA16(af[i], bf[j], acc[i][j]);
    __syncthreads();
  }

  const int rg = (ln >> 4) * 4;
#pragma unroll
  for (int i = 0; i < 4; ++i) {
#pragma unroll
    for (int j = 0; j < 4; ++j) {
      const int row = m0 + wr + i * 16 + rg;
      const int col = n0 + wc + j * 16 + lr;
#pragma unroll
      for (int q = 0; q < 4; ++q) {
        float v = acc[i][j][q];
        if (OUTBF) Cb[(size_t)(row + q) * N + col] = f2bf(v);
        else       Cf[(size_t)(row + q) * N + col] = v;
      }
    }
  }
}

// ---------------- depthwise causal conv1d + residual + route to Q/K/V ----------------
__global__ void k_conv_route(const u16* __restrict__ qkv, const float* __restrict__ cw,
                             u16* __restrict__ Qh, u16* __restrict__ Kh, u16* __restrict__ Vsd) {
  const int row = blockIdx.x;            // b*SEQL + s
  const int b = row >> 11, s = row & 2047;
  const int c = threadIdx.x * 8;         // 384 threads -> 3072 channels
  float x[4][8];
#pragma unroll
  for (int k = 0; k < 4; ++k) {
    const int sr = s + k - 3;
    if (sr < 0) {
#pragma unroll
      for (int j = 0; j < 8; ++j) x[k][j] = 0.f;
    } else {
      short8 v = *reinterpret_cast<const short8*>(&qkv[(size_t)(b * SEQL + sr) * TQKV + c]);
#pragma unroll
      for (int j = 0; j < 8; ++j) x[k][j] = bf2f((u16)v[j]);
    }
  }
  float o[8];
#pragma unroll
  for (int j = 0; j < 8; ++j) {
    float4 w4 = *reinterpret_cast<const float4*>(&cw[(c + j) * 4]);
    o[j] = x[3][j] + x[0][j] * w4.x + x[1][j] * w4.y + x[2][j] * w4.z + x[3][j] * w4.w;
  }
  short8 ov;
  if (c < QDIM) {
#pragma unroll
    for (int j = 0; j < 8; ++j) ov[j] = (short)f2bf(o[j] * QSCALE);
    const int h = c >> 7, d = c & 127;
    *reinterpret_cast<short8*>(&Qh[((size_t)(b * NH + h) * SEQL + s) * DH + d]) = ov;
  } else if (c < QDIM + KVDIM) {
#pragma unroll
    for (int j = 0; j < 8; ++j) ov[j] = (short)f2bf(o[j]);
    const int cc = c - QDIM;
    const int h = cc >> 7, d = cc & 127;
    *reinterpret_cast<short8*>(&Kh[((size_t)(b * NKV + h) * SEQL + s) * DH + d]) = ov;
  } else {
#pragma unroll
    for (int j = 0; j < 8; ++j) ov[j] = (short)f2bf(o[j]);
    const int cc = c - QDIM - KVDIM;
    const int h = cc >> 7, d = cc & 127;
    *reinterpret_cast<short8*>(&Vsd[((size_t)(b * NKV + h) * SEQL + s) * DH + d]) = ov;
  }
}

// ---------------- GQA causal flash attention: 8 waves x QBLK=32, KVBLK=64, 32x32 MFMA ----------------
// Swapped QK^T (S^T = K.Q^T) and swapped PV (O^T = V^T.P^T) keep the per-q softmax state
// lane-local (q = lane&31). K tile [64][128] and V^T tile [128][64] in LDS, XOR-swizzled
// (byte ^= (row&7)<<4), staged via global_load_lds with pre-swizzled global source.
__global__ __launch_bounds__(512) void k_attn(const u16* __restrict__ Qh, const u16* __restrict__ Kh,
                                              const u16* __restrict__ Vt, u16* __restrict__ att) {
  __shared__ u16 Ks[2][64 * 128];
  __shared__ u16 Vs[2][128 * 64];
  const int qb = blockIdx.x, h = blockIdx.y, b = blockIdx.z;
  const int kvh = h >> 2;
  const int tid = threadIdx.x, wv = tid >> 6, ln = tid & 63;
  const int lq = ln & 31, hi = ln >> 5;
  const int hi16 = hi * 16;
  const int q0w = qb * 256 + wv * 32;
  const int qg = q0w + lq;
  const int swr = (lq & 7) << 4;

  // Q fragments: B-frag for swapped QK^T -> col q = lane&31, k-chunk = hi*8
  const u16* qrow = Qh + ((size_t)(b * NH + h) * SEQL + qg) * DH;
  short8 qf[8];
#pragma unroll
  for (int dblk = 0; dblk < 8; ++dblk)
    qf[dblk] = *reinterpret_cast<const short8*>(qrow + dblk * 16 + hi * 8);

  const u16* kg = Kh + (size_t)(b * NKV + kvh) * SEQL * DH;
  const u16* vg = Vt + (size_t)(b * NKV + kvh) * DH * SEQL;

  // staging geometry: per thread 2 K chunks + 2 V chunks of 16B; LDS linear dest,
  // global source pre-swizzled so the swizzled ds_read sees K[row][col^sw].
  const int ck0 = tid, ck1 = tid + 512;
  const int krow0 = ck0 >> 4, kcb0 = (ck0 & 15) << 4;
  const int krow1 = ck1 >> 4, kcb1 = (ck1 & 15) << 4;
  const int koff0 = krow0 * DH + ((kcb0 ^ ((krow0 & 7) << 4)) >> 1);
  const int koff1 = krow1 * DH + ((kcb1 ^ ((krow1 & 7) << 4)) >> 1);
  const int vd0 = ck0 >> 3, vcb0 = (ck0 & 7) << 4;
  const int vd1 = ck1 >> 3, vcb1 = (ck1 & 7) << 4;
  const int voff0 = vd0 * SEQL + ((vcb0 ^ ((vd0 & 7) << 4)) >> 1);
  const int voff1 = vd1 * SEQL + ((vcb1 ^ ((vd1 & 7) << 4)) >> 1);

  auto stage = [&](int buf, int kvs) {
    gload16(kg + (size_t)kvs * DH + koff0, &Ks[buf][ck0 * 8]);
    gload16(kg + (size_t)kvs * DH + koff1, &Ks[buf][ck1 * 8]);
    gload16(vg + (size_t)kvs + voff0, &Vs[buf][ck0 * 8]);
    gload16(vg + (size_t)kvs + voff1, &Vs[buf][ck1 * 8]);
  };

  f32x16 oacc[4];
#pragma unroll
  for (int nb = 0; nb < 4; ++nb)
#pragma unroll
    for (int r = 0; r < 16; ++r) oacc[nb][r] = 0.f;
  float mrow = -1e30f, lrow = 0.f;

  const int ntiles = (qb + 1) * 4;
  stage(0, 0);
  __syncthreads();

  for (int t = 0; t < ntiles; ++t) {
    const int cur = t & 1;
    const int kvs = t * 64;
    if (t + 1 < ntiles) stage(cur ^ 1, kvs + 64);
    if (kvs <= q0w + 31) {
      const u16* ks = Ks[cur];
      const u16* vs = Vs[cur];
      f32x16 st[2];
#pragma unroll
      for (int kvb = 0; kvb < 2; ++kvb)
#pragma unroll
        for (int r = 0; r < 16; ++r) st[kvb][r] = 0.f;

      // S^T = K . Q^T  (A = K rows kv, B = Q^T cols q)
      __builtin_amdgcn_s_setprio(1);
#pragma unroll
      for (int kvb = 0; kvb < 2; ++kvb) {
        const u16* krow = ks + (kvb * 32 + lq) * 128;
#pragma unroll
        for (int dblk = 0; dblk < 8; ++dblk) {
          short8 kf = *reinterpret_cast<const short8*>(krow + (((dblk * 32 + hi16) ^ swr) >> 1));
          st[kvb] = MFMA32(kf, qf[dblk], st[kvb]);
        }
      }
      __builtin_amdgcn_s_setprio(0);

      // causal mask: kv row of reg r = (r&3)+8*(r>>2)+4*hi
      if (kvs + 63 > q0w) {
#pragma unroll
        for (int kvb = 0; kvb < 2; ++kvb)
#pragma unroll
          for (int r = 0; r < 16; ++r) {
            const int kvg = kvs + kvb * 32 + (r & 3) + 8 * (r >> 2) + 4 * hi;
            if (kvg > qg) st[kvb][r] = -1e30f;
          }
      }

      // online softmax, lane-local (row q = lq); halves combined via shfl_xor 32
      float tm = st[0][0];
#pragma unroll
      for (int kvb = 0; kvb < 2; ++kvb)
#pragma unroll
        for (int r = 0; r < 16; ++r) tm = fmaxf(tm, st[kvb][r]);
      tm = fmaxf(tm, __shfl_xor(tm, 32));
      if (__any(tm > mrow + 8.f)) {            // T13 defer-max
        const float nm = fmaxf(mrow, tm);
        const float scl = __expf(mrow - nm);
        mrow = nm;
        lrow *= scl;
#pragma unroll
        for (int nb = 0; nb < 4; ++nb)
#pragma unroll
          for (int r = 0; r < 16; ++r) oacc[nb][r] *= scl;
      }
      float ps = 0.f;
#pragma unroll
      for (int kvb = 0; kvb < 2; ++kvb)
#pragma unroll
        for (int r = 0; r < 16; ++r) {
          const float p = __expf(st[kvb][r] - mrow);
          st[kvb][r] = p;
          ps += p;
        }
      ps += __shfl_xor(ps, 32);
      lrow += ps;

      // pack P^T fragments (T12): pa[kc] elem j = P[q=lq][kc*16 + hi*8 + j]
      uint32_t w[4][4];
#pragma unroll
      for (int kvb = 0; kvb < 2; ++kvb) {
        uint32_t x0 = cvtpk(st[kvb][0], st[kvb][1]);
        uint32_t y0 = cvtpk(st[kvb][4], st[kvb][5]);
        swapln(x0, y0);
        uint32_t x1 = cvtpk(st[kvb][2], st[kvb][3]);
        uint32_t y1 = cvtpk(st[kvb][6], st[kvb][7]);
        swapln(x1, y1);
        w[kvb * 2][0] = x0; w[kvb * 2][1] = x1; w[kvb * 2][2] = y0; w[kvb * 2][3] = y1;
        uint32_t x2 = cvtpk(st[kvb][8], st[kvb][9]);
        uint32_t y2 = cvtpk(st[kvb][12], st[kvb][13]);
        swapln(x2, y2);
        uint32_t x3 = cvtpk(st[kvb][10], st[kvb][11]);
        uint32_t y3 = cvtpk(st[kvb][14], st[kvb][15]);
        swapln(x3, y3);
        w[kvb * 2 + 1][0] = x2; w[kvb * 2 + 1][1] = x3; w[kvb * 2 + 1][2] = y2; w[kvb * 2 + 1][3] = y3;
      }
      short8 pa[4];
#pragma unroll
      for (int kc = 0; kc < 4; ++kc) {
        union { uint32_t uw[4]; short8 s; } pu;
#pragma unroll
        for (int j = 0; j < 4; ++j) pu.uw[j] = w[kc][j];
        pa[kc] = pu.s;
      }

      // O^T += V^T . P^T  (A = V^T rows d, B = P^T cols q) -> col q lane-local
      __builtin_amdgcn_s_setprio(1);
#pragma unroll
      for (int nb = 0; nb < 4; ++nb) {
        const u16* vrow = vs + (nb * 32 + lq) * 64;
#pragma unroll
        for (int kc = 0; kc < 4; ++kc) {
          short8 vf = *reinterpret_cast<const short8*>(vrow + (((kc * 32 + hi16) ^ swr) >> 1));
          oacc[nb] = MFMA32(vf, pa[kc], oacc[nb]);
        }
      }
      __builtin_amdgcn_s_setprio(0);
    }
    __syncthreads();
  }

  // epilogue: O^T reg r -> d = nb*32 + (r&3)+8*(r>>2)+4*hi, q = lq (lane-local 1/l)
  const float inv = 1.0f / lrow;
  u16* orow = att + ((size_t)(b * SEQL + qg)) * QDIM + h * DH;
#pragma unroll
  for (int nb = 0; nb < 4; ++nb)
#pragma unroll
    for (int rg = 0; rg < 4; ++rg) {
      const int r = rg * 4;
      uint2 vout;
      vout.x = cvtpk(oacc[nb][r] * inv, oacc[nb][r + 1] * inv);
      vout.y = cvtpk(oacc[nb][r + 2] * inv, oacc[nb][r + 3] * inv);
      *reinterpret_cast<uint2*>(orow + nb * 32 + 8 * rg + 4 * hi) = vout;
    }
}

// ---------------- launch ----------------
extern "C" void kernel_launch(void* const* d_in, const int* in_sizes, int n_in,
                              void* d_out, int out_size, void* d_ws, size_t ws_size,
                              hipStream_t stream) {
  const float* hin = (const float*)d_in[0];
  const float* wq  = (const float*)d_in[1];
  const float* wk  = (const float*)d_in[2];
  const float* wvv = (const float*)d_in[3];
  const float* wo  = (const float*)d_in[4];
  const float* cw  = (const float*)d_in[5];
  float* out = (float*)d_out;
  char* ws = (char*)d_ws;

  u16* h_bf = (u16*)(ws + 0);                       // 16,777,216  [4096][2048]
  u16* Wt   = (u16*)(ws + 16777216);                // 12,582,912  [3072][2048]
  u16* Wot  = (u16*)(ws + 29360128);                //  8,388,608  [2048][2048]
  u16* Qh   = (u16*)(ws + 37748736);                // 16,777,216  [B][NH][S][DH]
  u16* Kh   = (u16*)(ws + 54525952);                //  4,194,304  [B][NKV][S][DH]
  u16* Vsd  = (u16*)(ws + 58720256);                //  4,194,304  [B][NKV][S][DH]
  u16* Vt   = (u16*)(ws + 62914560);                //  4,194,304  [B][NKV][DH][S]
  u16* att  = (u16*)(ws + 67108864);                // 16,777,216  [4096][2048]
  u16* qkv  = (u16*)d_out;                          // scratch reuse: 25,165,824 < 33,554,432

  dim3 tb(32, 8);
  k_f32_to_bf16<<<8192, 256, 0, stream>>>(hin, h_bf, MROWS * DM);
  k_transpose_f32_bf16<<<dim3(64, 64), tb, 0, stream>>>(wq, Wt, 2048, 2048, 0, 2048);
  k_transpose_f32_bf16<<<dim3(16, 64), tb, 0, stream>>>(wk, Wt, 2048, 512, 2048, 2048);
  k_transpose_f32_bf16<<<dim3(16, 64), tb, 0, stream>>>(wvv, Wt, 2048, 512, 2560, 2048);
  k_transpose_f32_bf16<<<dim3(64, 64), tb, 0, stream>>>(wo, Wot, 2048, 2048, 0, 2048);
  k_gemm_bt<1><<<dim3(32, 24), 256, 0, stream>>>(h_bf, Wt, nullptr, qkv, MROWS, TQKV, DM);
  k_conv_route<<<MROWS, 384, 0, stream>>>(qkv, cw, Qh, Kh, Vsd);
  k_transpose_bf16<<<dim3(4, 64, NB * NKV), tb, 0, stream>>>(Vsd, Vt, SEQL, DH);
  k_attn<<<dim3(SEQL / 256, NH, NB), 512, 0, stream>>>(Qh, Kh, Vt, att);
  k_gemm_bt<0><<<dim3(32, 16), 256, 0, stream>>>(att, Wot, out, nullptr, MROWS, DM, DM);
}